// Round 5
// baseline (1069.302 us; speedup 1.0000x reference)
//
#include <hip/hip_runtime.h>
#include <math.h>

#define Bdim 16
#define Mdim 4096
#define Tdim 4
#define Ddim 256
#define Vdim 40000
#define CONVMAX 512
#define MT 64

typedef float f32x4 __attribute__((ext_vector_type(4)));
static __device__ inline void nt_store4(float* p, float4 v) {
    f32x4 x = {v.x, v.y, v.z, v.w};
    __builtin_nontemporal_store(x, (f32x4*)p);
}

// ---------------------------------------------------------------------------
// init: out_uf = query_vector    grid: B blocks, 256 threads
// ---------------------------------------------------------------------------
__global__ void init_kernel(const float* __restrict__ qv, float* __restrict__ uf) {
    int b = blockIdx.x, i = threadIdx.x;
    uf[(size_t)b * Ddim + i] = qv[(size_t)b * Ddim + i];
}

// ---------------------------------------------------------------------------
// dot: D[v*16+b] = tab[v,:] . uf[b,:]
//   table part: thread=(b,y) owns full dot for rows y,y+16 (no reductions);
//   uf in LDS (stride 260 -> conflict-free); 16 same-row threads L1-merge.
//   hist part: Hdot[b,j] = hist[b,j,:] . uf[b,:], wave per row, shfl reduce.
// grid: DOT_TBLOCKS + HD_BLOCKS, 256 threads
// ---------------------------------------------------------------------------
#define DOT_VT 32
#define DOT_TBLOCKS (Vdim / DOT_VT)              // 1250
#define HD_JPB 32
#define HD_BLOCKS (Bdim * (CONVMAX / HD_JPB))    // 256
__global__ void dot_kernel(const float* __restrict__ tab, const float* __restrict__ uf,
                           const float* __restrict__ hist,
                           float* __restrict__ D, float* __restrict__ Hdot) {
    int bid = blockIdx.x, tid = threadIdx.x;
    if (bid < DOT_TBLOCKS) {
        __shared__ __align__(16) float ufs[Bdim][260];
#pragma unroll
        for (int i = 0; i < Bdim; ++i) ufs[i][tid] = uf[i * Ddim + tid];
        __syncthreads();
        int b = tid & 15, y = tid >> 4;
        int v = bid * DOT_VT + y;
        const float* r0 = tab + (size_t)v * Ddim;
        const float* r1 = r0 + 16 * Ddim;
        float a0 = 0.f, a1 = 0.f;
#pragma unroll 8
        for (int dq = 0; dq < 64; ++dq) {
            const float4 u  = *(const float4*)(&ufs[b][dq * 4]);
            const float4 x0 = *(const float4*)(r0 + dq * 4);
            const float4 x1 = *(const float4*)(r1 + dq * 4);
            a0 += x0.x * u.x + x0.y * u.y + x0.z * u.z + x0.w * u.w;
            a1 += x1.x * u.x + x1.y * u.y + x1.z * u.z + x1.w * u.w;
        }
        D[(size_t)v * Bdim + b]        = a0;   // = bid*512 + tid   (coalesced)
        D[(size_t)(v + 16) * Bdim + b] = a1;   // = bid*512 + 256 + tid
    } else {
        int r = bid - DOT_TBLOCKS;
        int b = r >> 4, j0 = (r & 15) * HD_JPB;
        int wave = tid >> 6, lane = tid & 63;
        const float4 u = *(const float4*)(uf + (size_t)b * Ddim + lane * 4);
        for (int j = j0 + wave; j < j0 + HD_JPB; j += 4) {
            const float4 h = *(const float4*)(hist + ((size_t)b * CONVMAX + j) * Ddim + lane * 4);
            float s = h.x * u.x + h.y * u.y + h.z * u.z + h.w * u.w;
#pragma unroll
            for (int off = 32; off > 0; off >>= 1) s += __shfl_xor(s, off, 64);
            if (lane == 0) Hdot[b * CONVMAX + j] = s;
        }
    }
}

// ---------------------------------------------------------------------------
// logit: logits[b,m] = gp * (sum_t D[st[t],b] + in_window * Hdot[b,m-kb])
// grid: B*M/256 blocks, 256 threads (thread per row)
// ---------------------------------------------------------------------------
__global__ void logit_kernel(const int* __restrict__ story, const int* __restrict__ kb_len,
                             const int* __restrict__ conv_len, const float* __restrict__ D,
                             const float* __restrict__ Hdot, const float* __restrict__ gp,
                             float* __restrict__ logits) {
    int row = blockIdx.x * 256 + threadIdx.x;
    int b = row >> 12, m = row & (Mdim - 1);
    const int4 st = *(const int4*)(story + (size_t)row * Tdim);
    float l = D[st.x * Bdim + b] + D[st.y * Bdim + b] + D[st.z * Bdim + b] + D[st.w * Bdim + b];
    unsigned j = (unsigned)(m - kb_len[b]);
    if (j < (unsigned)conv_len[b]) l += Hdot[b * CONVMAX + j];
    logits[row] = l * gp[row];
}

// ---------------------------------------------------------------------------
// stats (blocks < B) + zero w (next 625) + zero pwin (last 8)
// grid: B + ZW_BLOCKS + PW_BLOCKS, 256 threads
// ---------------------------------------------------------------------------
#define ZW_BLOCKS (Vdim * Bdim / 1024)           // 625
#define PW_BLOCKS (Bdim * CONVMAX / 1024)        // 8
__global__ void stats_zero_kernel(const float* __restrict__ logits, float* __restrict__ maxv,
                                  float* __restrict__ rsum, float* __restrict__ w,
                                  float* __restrict__ pwin) {
    int bid = blockIdx.x, tid = threadIdx.x;
    if (bid >= Bdim) {
        if (!w) return;
        int r = bid - Bdim;
        if (r < ZW_BLOCKS) {
            *(float4*)(w + r * 1024 + tid * 4) = make_float4(0.f, 0.f, 0.f, 0.f);
        } else {
            *(float4*)(pwin + (r - ZW_BLOCKS) * 1024 + tid * 4) = make_float4(0.f, 0.f, 0.f, 0.f);
        }
        return;
    }
    __shared__ float sh[256];
    const float* lg = logits + (size_t)bid * Mdim;
    float mx = -INFINITY;
    for (int i = tid; i < Mdim; i += 256) mx = fmaxf(mx, lg[i]);
    sh[tid] = mx; __syncthreads();
    for (int s = 128; s > 0; s >>= 1) { if (tid < s) sh[tid] = fmaxf(sh[tid], sh[tid + s]); __syncthreads(); }
    float bm = sh[0]; __syncthreads();
    float sm = 0.f;
    for (int i = tid; i < Mdim; i += 256) sm += expf(lg[i] - bm);
    sh[tid] = sm; __syncthreads();
    for (int s = 128; s > 0; s >>= 1) { if (tid < s) sh[tid] += sh[tid + s]; __syncthreads(); }
    if (tid == 0) { maxv[bid] = bm; rsum[bid] = 1.0f / sh[0]; }
}

// ---------------------------------------------------------------------------
// scatter: p = softmax(l)*gp; w[st[t],b] += p (x4 atomics); pwin for window
// grid: B*M/256 blocks, 256 threads (thread per row)
// ---------------------------------------------------------------------------
__global__ void scatter_kernel(const int* __restrict__ story, const int* __restrict__ kb_len,
                               const int* __restrict__ conv_len, const float* __restrict__ logits,
                               const float* __restrict__ maxv, const float* __restrict__ rsum,
                               const float* __restrict__ gp, float* __restrict__ w,
                               float* __restrict__ pwin) {
    int row = blockIdx.x * 256 + threadIdx.x;
    int b = row >> 12, m = row & (Mdim - 1);
    float p = expf(logits[row] - maxv[b]) * rsum[b] * gp[row];
    const int4 st = *(const int4*)(story + (size_t)row * Tdim);
    atomicAdd(&w[st.x * Bdim + b], p);
    atomicAdd(&w[st.y * Bdim + b], p);
    atomicAdd(&w[st.z * Bdim + b], p);
    atomicAdd(&w[st.w * Bdim + b], p);
    unsigned j = (unsigned)(m - kb_len[b]);
    if (j < (unsigned)conv_len[b]) pwin[b * CONVMAX + j] = p;
}

// ---------------------------------------------------------------------------
// wsum: uf[b,:] += sum_v w[v,b]*tab[v,:]
//   table part: wave per row (float4/lane, 1KB coalesced); w tile in LDS
//   read broadcast; 16 float4 register accumulators; per-wave atomics.
//   hist part: uf[b,:] += sum_j pwin[b,j]*hist[b,j,:] over 64-j chunks.
// grid: WS_TBLOCKS + WH_BLOCKS, 256 threads
// ---------------------------------------------------------------------------
#define WS_VT 64
#define WS_TBLOCKS (Vdim / WS_VT)                // 625
#define WH_JPB 64
#define WH_BLOCKS (Bdim * (CONVMAX / WH_JPB))    // 128
__global__ void wsum_kernel(const float* __restrict__ tab, const float* __restrict__ w,
                            const float* __restrict__ pwin, const float* __restrict__ hist,
                            float* __restrict__ uf) {
    int bid = blockIdx.x, tid = threadIdx.x;
    if (bid < WS_TBLOCKS) {
        __shared__ __align__(16) float ws[WS_VT][Bdim];
        int v0 = bid * WS_VT;
        {
            const float4* src = (const float4*)(w + (size_t)v0 * Bdim);
            ((float4*)ws)[tid] = src[tid];   // 256 float4 = 64x16 floats
        }
        __syncthreads();
        int wave = tid >> 6, lane = tid & 63;
        float4 acc[Bdim];
#pragma unroll
        for (int b = 0; b < Bdim; ++b) acc[b] = make_float4(0.f, 0.f, 0.f, 0.f);
        for (int i = 0; i < WS_VT / 4; ++i) {
            int vl = wave + i * 4;
            const float4 t = *(const float4*)(tab + (size_t)(v0 + vl) * Ddim + lane * 4);
            const float4 w0 = *(const float4*)(&ws[vl][0]);
            const float4 w1 = *(const float4*)(&ws[vl][4]);
            const float4 w2 = *(const float4*)(&ws[vl][8]);
            const float4 w3 = *(const float4*)(&ws[vl][12]);
            const float wv[Bdim] = { w0.x, w0.y, w0.z, w0.w, w1.x, w1.y, w1.z, w1.w,
                                     w2.x, w2.y, w2.z, w2.w, w3.x, w3.y, w3.z, w3.w };
#pragma unroll
            for (int b = 0; b < Bdim; ++b) {
                acc[b].x += wv[b] * t.x; acc[b].y += wv[b] * t.y;
                acc[b].z += wv[b] * t.z; acc[b].w += wv[b] * t.w;
            }
        }
#pragma unroll
        for (int b = 0; b < Bdim; ++b) {
            float* dst = uf + (size_t)b * Ddim + lane * 4;
            atomicAdd(dst + 0, acc[b].x);
            atomicAdd(dst + 1, acc[b].y);
            atomicAdd(dst + 2, acc[b].z);
            atomicAdd(dst + 3, acc[b].w);
        }
    } else {
        int r = bid - WS_TBLOCKS;
        int b = r >> 3, j0 = (r & 7) * WH_JPB;
        __shared__ float sp[WH_JPB];
        if (tid < WH_JPB) sp[tid] = pwin[b * CONVMAX + j0 + tid];
        __syncthreads();
        float acc = 0.f;
        const float* hb = hist + ((size_t)b * CONVMAX + j0) * Ddim + tid;
#pragma unroll 8
        for (int j = 0; j < WH_JPB; ++j) acc += sp[j] * hb[(size_t)j * Ddim];
        atomicAdd(&uf[(size_t)b * Ddim + tid], acc);
    }
}

// ---------------------------------------------------------------------------
// att: final hop only — recompute e3(row) by gather; prob = softmax*gp;
//      uf += sum_m prob*e3;  write e3 to out_m (NT) and psoft (NT).
// grid: B*(M/MT) blocks, 256 threads (wave per row, float4 per lane)
// ---------------------------------------------------------------------------
__global__ void att_kernel(const int* __restrict__ story, const int* __restrict__ kb_len,
                           const int* __restrict__ conv_len, const float* __restrict__ hist,
                           const float* __restrict__ tab, const float* __restrict__ logits,
                           const float* __restrict__ maxv, const float* __restrict__ rsum,
                           const float* __restrict__ gp,
                           float* __restrict__ uf_acc, float* __restrict__ out_m,
                           float* __restrict__ out_psoft) {
    int bid = blockIdx.x;
    int b  = bid / (Mdim / MT);
    int m0 = (bid % (Mdim / MT)) * MT;
    int tid = threadIdx.x, wave = tid >> 6, lane = tid & 63;
    int d4 = lane * 4;
    __shared__ float prob[MT];
    __shared__ float4 red[4][64];
    if (tid < MT) {
        size_t row = (size_t)b * Mdim + m0 + tid;
        float pn = expf(logits[row] - maxv[b]) * rsum[b];
        __builtin_nontemporal_store(pn, out_psoft + row);
        prob[tid] = pn * gp[row];
    }
    __syncthreads();
    int kb = kb_len[b], cl = conv_len[b];
    float4 acc = make_float4(0.f, 0.f, 0.f, 0.f);
#pragma unroll 4
    for (int mm = wave; mm < MT; mm += 4) {
        int m = m0 + mm;
        size_t row = (size_t)b * Mdim + m;
        const int* st = story + row * Tdim;
        float4 v = make_float4(0.f, 0.f, 0.f, 0.f);
#pragma unroll
        for (int t = 0; t < Tdim; ++t) {
            const float4 wv = *(const float4*)(tab + (size_t)st[t] * Ddim + d4);
            v.x += wv.x; v.y += wv.y; v.z += wv.z; v.w += wv.w;
        }
        if (m >= kb && m < kb + cl) {
            const float4 h = *(const float4*)(hist + ((size_t)b * CONVMAX + (m - kb)) * Ddim + d4);
            v.x += h.x; v.y += h.y; v.z += h.z; v.w += h.w;
        }
        nt_store4(out_m + row * Ddim + d4, v);
        float p = prob[mm];
        acc.x += p * v.x; acc.y += p * v.y; acc.z += p * v.z; acc.w += p * v.w;
    }
    red[wave][lane] = acc;
    __syncthreads();
    if (wave == 0) {
        float4 a0 = red[0][lane], a1 = red[1][lane], a2 = red[2][lane], a3 = red[3][lane];
        float* dst = uf_acc + (size_t)b * Ddim + d4;
        atomicAdd(dst + 0, a0.x + a1.x + a2.x + a3.x);
        atomicAdd(dst + 1, a0.y + a1.y + a2.y + a3.y);
        atomicAdd(dst + 2, a0.z + a1.z + a2.z + a3.z);
        atomicAdd(dst + 3, a0.w + a1.w + a2.w + a3.w);
    }
}

extern "C" void kernel_launch(void* const* d_in, const int* in_sizes, int n_in,
                              void* d_out, int out_size, void* d_ws, size_t ws_size,
                              hipStream_t stream) {
    const int*   story        = (const int*)d_in[0];
    const int*   kb_len       = (const int*)d_in[1];
    const int*   conv_len     = (const int*)d_in[2];
    // d_in[3] (query), d_in[8..11] (Tg_w, Tg_b, FW_w, FW_b): dead w.r.t. outputs
    const float* hist         = (const float*)d_in[4];
    const float* query_vector = (const float*)d_in[5];
    const float* gp           = (const float*)d_in[6];
    const float* C_emb        = (const float*)d_in[7];

    float* out        = (float*)d_out;
    float* out_psoft  = out;                                   // B*M
    float* out_logits = out + (size_t)Bdim * Mdim;             // B*M
    float* out_uf     = out + 2 * (size_t)Bdim * Mdim;         // B*D
    float* out_m      = out + 2 * (size_t)Bdim * Mdim + (size_t)Bdim * Ddim; // B*M*D

    float* ws = (float*)d_ws;
    float* D      = ws;                              // V*B      (640000)
    float* w      = D + (size_t)Vdim * Bdim;         // V*B      (640000)
    float* Hdot   = w + (size_t)Vdim * Bdim;         // B*CONVMAX
    float* pwin   = Hdot + Bdim * CONVMAX;           // B*CONVMAX
    float* logits = pwin + Bdim * CONVMAX;           // B*M
    float* maxv   = logits + (size_t)Bdim * Mdim;    // B
    float* rsum   = maxv + Bdim;                     // B

    const size_t TAB = (size_t)Vdim * Ddim;
    const float* tab0 = C_emb;
    const float* tab1 = C_emb + TAB;
    const float* tab2 = C_emb + 2 * TAB;
    const float* tab3 = C_emb + 3 * TAB;

    const int ROW_GRID = Bdim * Mdim / 256;                    // 256
    const int DOT_GRID = DOT_TBLOCKS + HD_BLOCKS;              // 1506
    const int SZ_GRID  = Bdim + ZW_BLOCKS + PW_BLOCKS;         // 649
    const int WS_GRID  = WS_TBLOCKS + WH_BLOCKS;               // 753
    const int ATT_GRID = Bdim * (Mdim / MT);                   // 1024

    init_kernel<<<Bdim, Ddim, 0, stream>>>(query_vector, out_uf);

    // hops 0 and 1: table-level passes only (no row gathers)
    const float* qtab[2] = { tab0, tab1 };
    const float* vtab[2] = { tab1, tab2 };
    for (int h = 0; h < 2; ++h) {
        dot_kernel<<<DOT_GRID, 256, 0, stream>>>(qtab[h], out_uf, hist, D, Hdot);
        logit_kernel<<<ROW_GRID, 256, 0, stream>>>(story, kb_len, conv_len, D, Hdot, gp, logits);
        stats_zero_kernel<<<SZ_GRID, 256, 0, stream>>>(logits, maxv, rsum, w, pwin);
        scatter_kernel<<<ROW_GRID, 256, 0, stream>>>(story, kb_len, conv_len, logits,
                                                     maxv, rsum, gp, w, pwin);
        wsum_kernel<<<WS_GRID, 256, 0, stream>>>(vtab[h], w, pwin, hist, out_uf);
    }

    // hop 2: logits/psoft are outputs; out_m forces one real gather pass
    dot_kernel<<<DOT_GRID, 256, 0, stream>>>(tab2, out_uf, hist, D, Hdot);
    logit_kernel<<<ROW_GRID, 256, 0, stream>>>(story, kb_len, conv_len, D, Hdot, gp, out_logits);
    stats_zero_kernel<<<Bdim, 256, 0, stream>>>(out_logits, maxv, rsum, nullptr, nullptr);
    att_kernel<<<ATT_GRID, 256, 0, stream>>>(story, kb_len, conv_len, hist, tab3,
                                             out_logits, maxv, rsum, gp,
                                             out_uf, out_m, out_psoft);
}

// Round 6
// 493.858 us; speedup vs baseline: 2.1652x; 2.1652x over previous
//
#include <hip/hip_runtime.h>
#include <math.h>

#define Bdim 16
#define Mdim 4096
#define Tdim 4
#define Ddim 256
#define Vdim 40000
#define CONVMAX 512

typedef float f32x4 __attribute__((ext_vector_type(4)));
static __device__ inline void nt_store4(float* p, float4 v) {
    f32x4 x = {v.x, v.y, v.z, v.w};
    __builtin_nontemporal_store(x, (f32x4*)p);
}

// ---------------------------------------------------------------------------
// init: out_uf = query_vector    grid: B blocks, 256 threads
// ---------------------------------------------------------------------------
__global__ void init_kernel(const float* __restrict__ qv, float* __restrict__ uf) {
    int b = blockIdx.x, i = threadIdx.x;
    uf[(size_t)b * Ddim + i] = qv[(size_t)b * Ddim + i];
}

// ---------------------------------------------------------------------------
// dot: D[v*16+b] = tab[v,:] . uf[b,:]
//   table part: GEMM microtile. Block = 64 v-rows x 16 b; K chunked by 64 in
//   LDS (stride 68 floats -> 2-way bank aliasing only, free). Thread owns a
//   2v x 2b register tile. All global loads coalesced.
//   hist part: Hdot[b,j] = hist[b,j,:] . uf[b,:], wave per row, shfl reduce.
// grid: DOT_TBLOCKS + HD_BLOCKS, 256 threads
// ---------------------------------------------------------------------------
#define DOT_VT 64
#define DOT_TBLOCKS (Vdim / DOT_VT)              // 625
#define DOT_KC 64
#define HD_JPB 32
#define HD_BLOCKS (Bdim * (CONVMAX / HD_JPB))    // 256
__global__ void dot_kernel(const float* __restrict__ tab, const float* __restrict__ uf,
                           const float* __restrict__ hist,
                           float* __restrict__ D, float* __restrict__ Hdot) {
    int bid = blockIdx.x, tid = threadIdx.x;
    if (bid < DOT_TBLOCKS) {
        __shared__ __align__(16) float tl[DOT_VT][DOT_KC + 4];   // 17.4 KB
        __shared__ __align__(16) float ufl[Bdim][DOT_KC + 4];    //  4.4 KB
        int v0 = bid * DOT_VT;
        int vl = tid >> 3;             // 0..31
        int bl = tid & 7;              // 0..7
        int vA = vl * 2, vB = vA + 1;
        int b0 = bl * 2, b1 = b0 + 1;
        float aA0 = 0.f, aA1 = 0.f, aB0 = 0.f, aB1 = 0.f;
        for (int kc = 0; kc < Ddim; kc += DOT_KC) {
            __syncthreads();
            // stage tab tile: 64 rows x 64 floats (coalesced 256 B/row segs)
#pragma unroll
            for (int i = 0; i < 4; ++i) {
                int idx = tid + i * 256;           // 1024 float4 total
                int r = idx >> 4, c4 = idx & 15;
                *(float4*)(&tl[r][c4 * 4]) =
                    *(const float4*)(tab + (size_t)(v0 + r) * Ddim + kc + c4 * 4);
            }
            {   // stage uf tile: 16 x 64 floats
                int r = tid >> 4, c4 = tid & 15;
                *(float4*)(&ufl[r][c4 * 4]) =
                    *(const float4*)(uf + (size_t)r * Ddim + kc + c4 * 4);
            }
            __syncthreads();
#pragma unroll
            for (int k4 = 0; k4 < DOT_KC / 4; ++k4) {
                const float4 a  = *(const float4*)(&tl[vA][k4 * 4]);
                const float4 c  = *(const float4*)(&tl[vB][k4 * 4]);
                const float4 u0 = *(const float4*)(&ufl[b0][k4 * 4]);
                const float4 u1 = *(const float4*)(&ufl[b1][k4 * 4]);
                aA0 += a.x * u0.x + a.y * u0.y + a.z * u0.z + a.w * u0.w;
                aA1 += a.x * u1.x + a.y * u1.y + a.z * u1.z + a.w * u1.w;
                aB0 += c.x * u0.x + c.y * u0.y + c.z * u0.z + c.w * u0.w;
                aB1 += c.x * u1.x + c.y * u1.y + c.z * u1.z + c.w * u1.w;
            }
        }
        size_t base = (size_t)(v0 + vA) * Bdim;
        D[base + b0] = aA0;  D[base + b1] = aA1;
        D[base + Bdim + b0] = aB0;  D[base + Bdim + b1] = aB1;
    } else {
        int r = bid - DOT_TBLOCKS;
        int b = r >> 4, j0 = (r & 15) * HD_JPB;
        int wave = tid >> 6, lane = tid & 63;
        const float4 u = *(const float4*)(uf + (size_t)b * Ddim + lane * 4);
        for (int j = j0 + wave; j < j0 + HD_JPB; j += 4) {
            const float4 h = *(const float4*)(hist + ((size_t)b * CONVMAX + j) * Ddim + lane * 4);
            float s = h.x * u.x + h.y * u.y + h.z * u.z + h.w * u.w;
#pragma unroll
            for (int off = 32; off > 0; off >>= 1) s += __shfl_xor(s, off, 64);
            if (lane == 0) Hdot[b * CONVMAX + j] = s;
        }
    }
}

// ---------------------------------------------------------------------------
// logit: logits[b,m] = gp * (sum_t D[st[t],b] + in_window * Hdot[b,m-kb])
// grid: B*M/256 blocks, 256 threads (thread per row)
// ---------------------------------------------------------------------------
__global__ void logit_kernel(const int* __restrict__ story, const int* __restrict__ kb_len,
                             const int* __restrict__ conv_len, const float* __restrict__ D,
                             const float* __restrict__ Hdot, const float* __restrict__ gp,
                             float* __restrict__ logits) {
    int row = blockIdx.x * 256 + threadIdx.x;
    int b = row >> 12, m = row & (Mdim - 1);
    const int4 st = *(const int4*)(story + (size_t)row * Tdim);
    float l = D[st.x * Bdim + b] + D[st.y * Bdim + b] + D[st.z * Bdim + b] + D[st.w * Bdim + b];
    unsigned j = (unsigned)(m - kb_len[b]);
    if (j < (unsigned)conv_len[b]) l += Hdot[b * CONVMAX + j];
    logits[row] = l * gp[row];
}

// ---------------------------------------------------------------------------
// stats (blocks < B) + zero w (next 625) + zero pwin (last 8)
// grid: B [+ ZW_BLOCKS + PW_BLOCKS], 256 threads
// ---------------------------------------------------------------------------
#define ZW_BLOCKS (Vdim * Bdim / 1024)           // 625
#define PW_BLOCKS (Bdim * CONVMAX / 1024)        // 8
__global__ void stats_zero_kernel(const float* __restrict__ logits, float* __restrict__ maxv,
                                  float* __restrict__ rsum, float* __restrict__ w,
                                  float* __restrict__ pwin) {
    int bid = blockIdx.x, tid = threadIdx.x;
    if (bid >= Bdim) {
        int r = bid - Bdim;
        if (r < ZW_BLOCKS) {
            *(float4*)(w + r * 1024 + tid * 4) = make_float4(0.f, 0.f, 0.f, 0.f);
        } else {
            *(float4*)(pwin + (r - ZW_BLOCKS) * 1024 + tid * 4) = make_float4(0.f, 0.f, 0.f, 0.f);
        }
        return;
    }
    __shared__ float sh[256];
    const float* lg = logits + (size_t)bid * Mdim;
    float mx = -INFINITY;
    for (int i = tid; i < Mdim; i += 256) mx = fmaxf(mx, lg[i]);
    sh[tid] = mx; __syncthreads();
    for (int s = 128; s > 0; s >>= 1) { if (tid < s) sh[tid] = fmaxf(sh[tid], sh[tid + s]); __syncthreads(); }
    float bm = sh[0]; __syncthreads();
    float sm = 0.f;
    for (int i = tid; i < Mdim; i += 256) sm += expf(lg[i] - bm);
    sh[tid] = sm; __syncthreads();
    for (int s = 128; s > 0; s >>= 1) { if (tid < s) sh[tid] += sh[tid + s]; __syncthreads(); }
    if (tid == 0) { maxv[bid] = bm; rsum[bid] = 1.0f / sh[0]; }
}

// ---------------------------------------------------------------------------
// scatter: p = softmax(l)*gp; w[st[t],b] += p (x4 atomics, ~uniform over
// 640K addrs -> low contention); pwin for window
// grid: B*M/256 blocks, 256 threads (thread per row)
// ---------------------------------------------------------------------------
__global__ void scatter_kernel(const int* __restrict__ story, const int* __restrict__ kb_len,
                               const int* __restrict__ conv_len, const float* __restrict__ logits,
                               const float* __restrict__ maxv, const float* __restrict__ rsum,
                               const float* __restrict__ gp, float* __restrict__ w,
                               float* __restrict__ pwin) {
    int row = blockIdx.x * 256 + threadIdx.x;
    int b = row >> 12, m = row & (Mdim - 1);
    float p = expf(logits[row] - maxv[b]) * rsum[b] * gp[row];
    const int4 st = *(const int4*)(story + (size_t)row * Tdim);
    atomicAdd(&w[st.x * Bdim + b], p);
    atomicAdd(&w[st.y * Bdim + b], p);
    atomicAdd(&w[st.z * Bdim + b], p);
    atomicAdd(&w[st.w * Bdim + b], p);
    unsigned j = (unsigned)(m - kb_len[b]);
    if (j < (unsigned)conv_len[b]) pwin[b * CONVMAX + j] = p;
}

// ---------------------------------------------------------------------------
// wsum: partial[s][b][:] = sum_{v in chunk s} w[v,b]*tab[v,:]   (NO atomics)
//   table part: wave owns 4 b's across an 80-row chunk; w tile in LDS
//   (broadcast); full-row coalesced tab loads; non-atomic partial store.
//   hist part: histpart[b*8+c][:] = sum_j pwin*hist over 64-j chunk.
// grid: WS_TBLOCKS + WH_BLOCKS, 256 threads
// ---------------------------------------------------------------------------
#define WS_VT 80
#define WS_TBLOCKS (Vdim / WS_VT)                // 500
#define WH_JPB 64
#define WH_BLOCKS (Bdim * (CONVMAX / WH_JPB))    // 128
__global__ void wsum_kernel(const float* __restrict__ tab, const float* __restrict__ w,
                            const float* __restrict__ pwin, const float* __restrict__ hist,
                            float* __restrict__ partial, float* __restrict__ histpart) {
    int bid = blockIdx.x, tid = threadIdx.x;
    if (bid < WS_TBLOCKS) {
        __shared__ float ws[WS_VT][Bdim];        // 5 KB
        int v0 = bid * WS_VT;
        for (int i = tid; i < WS_VT * Bdim; i += 256) ((float*)ws)[i] = w[(size_t)v0 * Bdim + i];
        __syncthreads();
        int wave = tid >> 6, lane = tid & 63;
        int b0 = wave * 4, d4 = lane * 4;
        float4 a0 = make_float4(0.f,0.f,0.f,0.f), a1 = a0, a2 = a0, a3 = a0;
        for (int v = 0; v < WS_VT; ++v) {
            const float4 t = *(const float4*)(tab + (size_t)(v0 + v) * Ddim + d4);
            float w0 = ws[v][b0], w1 = ws[v][b0+1], w2 = ws[v][b0+2], w3 = ws[v][b0+3];
            a0.x += w0*t.x; a0.y += w0*t.y; a0.z += w0*t.z; a0.w += w0*t.w;
            a1.x += w1*t.x; a1.y += w1*t.y; a1.z += w1*t.z; a1.w += w1*t.w;
            a2.x += w2*t.x; a2.y += w2*t.y; a2.z += w2*t.z; a2.w += w2*t.w;
            a3.x += w3*t.x; a3.y += w3*t.y; a3.z += w3*t.z; a3.w += w3*t.w;
        }
        float* dst = partial + ((size_t)bid * Bdim + b0) * Ddim + d4;
        *(float4*)(dst)            = a0;
        *(float4*)(dst + Ddim)     = a1;
        *(float4*)(dst + 2 * Ddim) = a2;
        *(float4*)(dst + 3 * Ddim) = a3;
    } else {
        int r = bid - WS_TBLOCKS;
        int b = r >> 3, j0 = (r & 7) * WH_JPB;
        __shared__ float sp[WH_JPB];
        if (tid < WH_JPB) sp[tid] = pwin[b * CONVMAX + j0 + tid];
        __syncthreads();
        float acc = 0.f;
        const float* hb = hist + ((size_t)b * CONVMAX + j0) * Ddim + tid;
#pragma unroll 8
        for (int j = 0; j < WH_JPB; ++j) acc += sp[j] * hb[(size_t)j * Ddim];
        histpart[(size_t)r * Ddim + tid] = acc;
    }
}

// ---------------------------------------------------------------------------
// ufred: uf[b,:] += sum_s partial[s][b][:] + sum_c histpart[b*8+c][:]
// grid: B blocks, 256 threads (4 waves split the 500 slabs)
// ---------------------------------------------------------------------------
__global__ void ufred_kernel(const float* __restrict__ partial, const float* __restrict__ histpart,
                             float* __restrict__ uf) {
    int b = blockIdx.x, tid = threadIdx.x;
    int wave = tid >> 6, lane = tid & 63, d4 = lane * 4;
    float4 acc = make_float4(0.f, 0.f, 0.f, 0.f);
    for (int s = wave; s < WS_TBLOCKS; s += 4) {
        const float4 p = *(const float4*)(partial + ((size_t)s * Bdim + b) * Ddim + d4);
        acc.x += p.x; acc.y += p.y; acc.z += p.z; acc.w += p.w;
    }
    if (wave == 0) {
#pragma unroll
        for (int c = 0; c < 8; ++c) {
            const float4 h = *(const float4*)(histpart + ((size_t)(b * 8 + c)) * Ddim + d4);
            acc.x += h.x; acc.y += h.y; acc.z += h.z; acc.w += h.w;
        }
    }
    __shared__ float4 red[4][64];
    red[wave][lane] = acc;
    __syncthreads();
    if (wave == 0) {
        float4 r0 = red[0][lane], r1 = red[1][lane], r2 = red[2][lane], r3 = red[3][lane];
        float* dst = uf + (size_t)b * Ddim + d4;
        float4 cur = *(const float4*)dst;
        cur.x += r0.x + r1.x + r2.x + r3.x;
        cur.y += r0.y + r1.y + r2.y + r3.y;
        cur.z += r0.z + r1.z + r2.z + r3.z;
        cur.w += r0.w + r1.w + r2.w + r3.w;
        *(float4*)dst = cur;
    }
}

// ---------------------------------------------------------------------------
// att: final hop — recompute e3(row) by gather; prob = softmax*gp;
//      attpart[block] = sum_m prob*e3 (NO atomics); e3 -> out_m (NT);
//      gp-free softmax -> psoft (NT).
// grid: B*(M/MT) = 2048 blocks, 256 threads (wave per row)
// ---------------------------------------------------------------------------
#define MT 32
#define ATT_CH (Mdim / MT)                       // 128
__global__ void att_kernel(const int* __restrict__ story, const int* __restrict__ kb_len,
                           const int* __restrict__ conv_len, const float* __restrict__ hist,
                           const float* __restrict__ tab, const float* __restrict__ logits,
                           const float* __restrict__ maxv, const float* __restrict__ rsum,
                           const float* __restrict__ gp,
                           float* __restrict__ attpart, float* __restrict__ out_m,
                           float* __restrict__ out_psoft) {
    int bid = blockIdx.x;
    int b  = bid / ATT_CH;
    int m0 = (bid % ATT_CH) * MT;
    int tid = threadIdx.x, wave = tid >> 6, lane = tid & 63;
    int d4 = lane * 4;
    __shared__ float prob[MT];
    __shared__ float4 red[4][64];
    if (tid < MT) {
        size_t row = (size_t)b * Mdim + m0 + tid;
        float pn = expf(logits[row] - maxv[b]) * rsum[b];
        __builtin_nontemporal_store(pn, out_psoft + row);
        prob[tid] = pn * gp[row];
    }
    __syncthreads();
    int kb = kb_len[b], cl = conv_len[b];
    float4 acc = make_float4(0.f, 0.f, 0.f, 0.f);
#pragma unroll 4
    for (int mm = wave; mm < MT; mm += 4) {
        int m = m0 + mm;
        size_t row = (size_t)b * Mdim + m;
        const int* st = story + row * Tdim;
        float4 v = make_float4(0.f, 0.f, 0.f, 0.f);
#pragma unroll
        for (int t = 0; t < Tdim; ++t) {
            const float4 wv = *(const float4*)(tab + (size_t)st[t] * Ddim + d4);
            v.x += wv.x; v.y += wv.y; v.z += wv.z; v.w += wv.w;
        }
        if (m >= kb && m < kb + cl) {
            const float4 h = *(const float4*)(hist + ((size_t)b * CONVMAX + (m - kb)) * Ddim + d4);
            v.x += h.x; v.y += h.y; v.z += h.z; v.w += h.w;
        }
        nt_store4(out_m + row * Ddim + d4, v);
        float p = prob[mm];
        acc.x += p * v.x; acc.y += p * v.y; acc.z += p * v.z; acc.w += p * v.w;
    }
    red[wave][lane] = acc;
    __syncthreads();
    if (wave == 0) {
        float4 a0 = red[0][lane], a1 = red[1][lane], a2 = red[2][lane], a3 = red[3][lane];
        float4 t;
        t.x = a0.x + a1.x + a2.x + a3.x;
        t.y = a0.y + a1.y + a2.y + a3.y;
        t.z = a0.z + a1.z + a2.z + a3.z;
        t.w = a0.w + a1.w + a2.w + a3.w;
        *(float4*)(attpart + (size_t)bid * Ddim + d4) = t;
    }
}

// ---------------------------------------------------------------------------
// attred: out_uf[b,:] += sum_c attpart[b*128+c][:]   grid: B blocks, 256 thr
// ---------------------------------------------------------------------------
__global__ void attred_kernel(const float* __restrict__ attpart, float* __restrict__ uf) {
    int b = blockIdx.x, tid = threadIdx.x;
    int wave = tid >> 6, lane = tid & 63, d4 = lane * 4;
    float4 acc = make_float4(0.f, 0.f, 0.f, 0.f);
    for (int c = wave; c < ATT_CH; c += 4) {
        const float4 p = *(const float4*)(attpart + ((size_t)(b * ATT_CH + c)) * Ddim + d4);
        acc.x += p.x; acc.y += p.y; acc.z += p.z; acc.w += p.w;
    }
    __shared__ float4 red[4][64];
    red[wave][lane] = acc;
    __syncthreads();
    if (wave == 0) {
        float4 r0 = red[0][lane], r1 = red[1][lane], r2 = red[2][lane], r3 = red[3][lane];
        float* dst = uf + (size_t)b * Ddim + d4;
        float4 cur = *(const float4*)dst;
        cur.x += r0.x + r1.x + r2.x + r3.x;
        cur.y += r0.y + r1.y + r2.y + r3.y;
        cur.z += r0.z + r1.z + r2.z + r3.z;
        cur.w += r0.w + r1.w + r2.w + r3.w;
        *(float4*)dst = cur;
    }
}

extern "C" void kernel_launch(void* const* d_in, const int* in_sizes, int n_in,
                              void* d_out, int out_size, void* d_ws, size_t ws_size,
                              hipStream_t stream) {
    const int*   story        = (const int*)d_in[0];
    const int*   kb_len       = (const int*)d_in[1];
    const int*   conv_len     = (const int*)d_in[2];
    // d_in[3] (query), d_in[8..11] (Tg_w, Tg_b, FW_w, FW_b): dead w.r.t. outputs
    const float* hist         = (const float*)d_in[4];
    const float* query_vector = (const float*)d_in[5];
    const float* gp           = (const float*)d_in[6];
    const float* C_emb        = (const float*)d_in[7];

    float* out        = (float*)d_out;
    float* out_psoft  = out;                                   // B*M
    float* out_logits = out + (size_t)Bdim * Mdim;             // B*M
    float* out_uf     = out + 2 * (size_t)Bdim * Mdim;         // B*D
    float* out_m      = out + 2 * (size_t)Bdim * Mdim + (size_t)Bdim * Ddim; // B*M*D

    float* ws = (float*)d_ws;
    float* D        = ws;                                  // V*B
    float* w        = D + (size_t)Vdim * Bdim;             // V*B
    float* Hdot     = w + (size_t)Vdim * Bdim;             // B*CONVMAX
    float* pwin     = Hdot + Bdim * CONVMAX;               // B*CONVMAX
    float* logits   = pwin + Bdim * CONVMAX;               // B*M
    float* maxv     = logits + (size_t)Bdim * Mdim;        // B
    float* rsum     = maxv + Bdim;                         // B
    float* partial  = rsum + Bdim;                         // 500*16*256
    float* histpart = partial + (size_t)WS_TBLOCKS * Bdim * Ddim;   // 128*256
    float* attpart  = histpart + (size_t)WH_BLOCKS * Ddim;          // 2048*256

    const size_t TAB = (size_t)Vdim * Ddim;
    const float* tab0 = C_emb;
    const float* tab1 = C_emb + TAB;
    const float* tab2 = C_emb + 2 * TAB;
    const float* tab3 = C_emb + 3 * TAB;

    const int ROW_GRID = Bdim * Mdim / 256;                    // 256
    const int DOT_GRID = DOT_TBLOCKS + HD_BLOCKS;              // 881
    const int SZ_GRID  = Bdim + ZW_BLOCKS + PW_BLOCKS;         // 649
    const int WS_GRID  = WS_TBLOCKS + WH_BLOCKS;               // 628
    const int ATT_GRID = Bdim * ATT_CH;                        // 2048

    init_kernel<<<Bdim, Ddim, 0, stream>>>(query_vector, out_uf);

    // hops 0 and 1: table-level passes only (no row gathers, no hot atomics)
    const float* qtab[2] = { tab0, tab1 };
    const float* vtab[2] = { tab1, tab2 };
    for (int h = 0; h < 2; ++h) {
        dot_kernel<<<DOT_GRID, 256, 0, stream>>>(qtab[h], out_uf, hist, D, Hdot);
        logit_kernel<<<ROW_GRID, 256, 0, stream>>>(story, kb_len, conv_len, D, Hdot, gp, logits);
        stats_zero_kernel<<<SZ_GRID, 256, 0, stream>>>(logits, maxv, rsum, w, pwin);
        scatter_kernel<<<ROW_GRID, 256, 0, stream>>>(story, kb_len, conv_len, logits,
                                                     maxv, rsum, gp, w, pwin);
        wsum_kernel<<<WS_GRID, 256, 0, stream>>>(vtab[h], w, pwin, hist, partial, histpart);
        ufred_kernel<<<Bdim, 256, 0, stream>>>(partial, histpart, out_uf);
    }

    // hop 2: logits/psoft are outputs; out_m forces one real gather pass
    dot_kernel<<<DOT_GRID, 256, 0, stream>>>(tab2, out_uf, hist, D, Hdot);
    logit_kernel<<<ROW_GRID, 256, 0, stream>>>(story, kb_len, conv_len, D, Hdot, gp, out_logits);
    stats_zero_kernel<<<Bdim, 256, 0, stream>>>(out_logits, maxv, rsum, w, pwin);
    att_kernel<<<ATT_GRID, 256, 0, stream>>>(story, kb_len, conv_len, hist, tab3,
                                             out_logits, maxv, rsum, gp,
                                             attpart, out_m, out_psoft);
    attred_kernel<<<Bdim, 256, 0, stream>>>(attpart, out_uf);
}